// Round 3
// baseline (56.428 us; speedup 1.0000x reference)
//
#include <hip/hip_runtime.h>
#include <hip/hip_bf16.h>

// MoE: out[b] = inp[b] @ weight[gate[b]].T
// inp: [4096,512] f32, gate: [4096] int, weight: [32,512,512] f32, out: [4096,512] f32
// Round 3: 128x128x64 grouped bf16-MFMA GEMM (m97 shape), reg-staged f32->bf16 via
// cvt_pk, XOR-swizzled LDS, 1 barrier/K-tile, prep emits tile table, XCD swizzle.

#define NE     32
#define NBATCH 4096
#define KF     512
#define NF     512
#define BM     128           // token tile
#define BN     128           // out-feature tile
#define BK     64            // k tile
#define NKT    (KF / BK)     // 8
#define YT     64            // max (expert,local) tiles: 32 + 31 = 63, padded to 64

#define WS_COUNTS  0
#define WS_OFFSETS 32
#define WS_TABLE   64
#define WS_TOKENS  128

typedef __attribute__((ext_vector_type(8))) short bf16x8;   // 8 bf16 = 4 VGPR
typedef __attribute__((ext_vector_type(4))) float f32x4;

__device__ __forceinline__ unsigned cvt2(float lo, float hi) {
    __hip_bfloat162 h = __float22bfloat162_rn(make_float2(lo, hi));
    return *reinterpret_cast<unsigned*>(&h);   // v_cvt_pk_bf16_f32
}

// XOR swizzle within [row][64 bf16] (128B row stride); same bijection on write+read.
__device__ __forceinline__ int swz(int row, int col_b) {
    return (row * 128 + col_b) ^ ((row & 7) << 4);
}

// ---- fused prep: histogram + wave-scan + tile table + scatter, one block ----
__global__ __launch_bounds__(1024)
void moe_prep(const int* __restrict__ gate, int* __restrict__ ws) {
    __shared__ int cnt[NE], cur[NE];
    const int tid = threadIdx.x;
    if (tid < NE) cnt[tid] = 0;
    __syncthreads();
    int g[4];
#pragma unroll
    for (int i = 0; i < 4; ++i) {
        g[i] = gate[tid + i * 1024];
        atomicAdd(&cnt[g[i]], 1);
    }
    __syncthreads();
    if (tid < 64) {                       // wave 0 does all scans
        int c = (tid < NE) ? cnt[tid] : 0;
        int x = c;
#pragma unroll
        for (int d = 1; d < 32; d <<= 1) { int u = __shfl_up(x, d, 64); if (tid >= d) x += u; }
        int excl = x - c;                 // token offset
        if (tid < NE) {
            cur[tid] = excl;
            ws[WS_COUNTS + tid]  = c;
            ws[WS_OFFSETS + tid] = excl;
        }
        int nt = (c + BM - 1) / BM;       // tiles for this expert
        int t = nt;
#pragma unroll
        for (int d = 1; d < 32; d <<= 1) { int u = __shfl_up(t, d, 64); if (tid >= d) t += u; }
        int texcl = t - nt;
        int tot = __shfl(t, 31, 64);      // total tiles
        if (tid < NE)
            for (int k = 0; k < nt; ++k) ws[WS_TABLE + texcl + k] = (tid << 16) | k;
        for (int y = tid; y < YT; y += 64)
            if (y >= tot) ws[WS_TABLE + y] = -1;
    }
    __syncthreads();
#pragma unroll
    for (int i = 0; i < 4; ++i) {
        int pos = atomicAdd(&cur[g[i]], 1);
        ws[WS_TOKENS + pos] = tid + i * 1024;
    }
}

// ---- grouped MFMA GEMM: 128x128 tile, 4 waves, 64x64 per wave ----
__global__ __launch_bounds__(256)
void moe_gemm(const float* __restrict__ inp,
              const float* __restrict__ weight,
              const int* __restrict__ ws,
              float* __restrict__ out) {
    // XCD-chunked bijective swizzle: grid=256, 8 XCDs, 32 blocks/XCD chunk.
    const int bid = blockIdx.x;
    const int swb = (bid & 7) * 32 + (bid >> 3);
    const int nb  = swb & 3;              // n-tile (fastest -> same expert tiles adjacent)
    const int y   = swb >> 2;             // (expert, local) tile id

    const int entry = ws[WS_TABLE + y];
    if (entry < 0) return;
    const int e     = entry >> 16;
    const int local = entry & 0xffff;
    const int off   = ws[WS_OFFSETS + e];
    const int cnt   = ws[WS_COUNTS + e];
    const int* tokens = ws + WS_TOKENS;

    const int m0   = local * BM;
    const int mcnt = min(BM, cnt - m0);
    const int nblk = nb * BN;

    __shared__ __align__(16) unsigned char lds[2][(BM + BN) * BK * 2]; // 2 x 32KB
    __shared__ int srow[BM];

    const int tid  = threadIdx.x;
    const int lane = tid & 63;
    const int wid  = tid >> 6;
    const int wm   = wid & 1;             // m half (64 rows)
    const int wn   = wid >> 1;            // n half (64 cols)

    if (tid < BM) srow[tid] = (tid < mcnt) ? tokens[off + m0 + tid] : -1;
    __syncthreads();

    // rows this thread stages: slot s = tid + i*256, r = s>>4 = (tid>>4) + 16*i
    int arow[8];
#pragma unroll
    for (int i = 0; i < 8; ++i) arow[i] = srow[(tid >> 4) + 16 * i];

    const float* wbase = weight + (size_t)e * (NF * KF) + (size_t)nblk * KF;

    float4 ra[8], rw[8];

#define LOAD_TILE(T) do { const int k0 = (T) * BK; const int c4 = (tid & 15) * 4;    \
    _Pragma("unroll") for (int i = 0; i < 8; ++i) {                                  \
        ra[i] = (arow[i] >= 0)                                                       \
            ? *(const float4*)(inp + (size_t)arow[i] * KF + k0 + c4)                 \
            : make_float4(0.f, 0.f, 0.f, 0.f); }                                     \
    _Pragma("unroll") for (int i = 0; i < 8; ++i) {                                  \
        int r = (tid >> 4) + 16 * i;                                                 \
        rw[i] = *(const float4*)(wbase + (size_t)r * KF + k0 + c4); } } while (0)

#define WRITE_TILE(B) do { unsigned char* Lb = lds[B]; const int cb = (tid & 15) * 8;\
    _Pragma("unroll") for (int i = 0; i < 8; ++i) {                                  \
        int r = (tid >> 4) + 16 * i;                                                 \
        uint2 p = make_uint2(cvt2(ra[i].x, ra[i].y), cvt2(ra[i].z, ra[i].w));        \
        *(uint2*)(Lb + swz(r, cb)) = p; }                                            \
    _Pragma("unroll") for (int i = 0; i < 8; ++i) {                                  \
        int r = (tid >> 4) + 16 * i;                                                 \
        uint2 p = make_uint2(cvt2(rw[i].x, rw[i].y), cvt2(rw[i].z, rw[i].w));        \
        *(uint2*)(Lb + 16384 + swz(r, cb)) = p; } } while (0)

    f32x4 acc[4][4];
#pragma unroll
    for (int mi = 0; mi < 4; ++mi)
#pragma unroll
        for (int ni = 0; ni < 4; ++ni) acc[mi][ni] = (f32x4)(0.f);

#define COMPUTE(B) do { const unsigned char* Lb = lds[B];                            \
    _Pragma("unroll") for (int kk = 0; kk < 2; ++kk) {                               \
        const int kb = kk * 64 + 16 * (lane >> 4);                                   \
        bf16x8 af[4], bfr[4];                                                        \
        _Pragma("unroll") for (int mi = 0; mi < 4; ++mi) {                           \
            int r = wm * 64 + mi * 16 + (lane & 15);                                 \
            af[mi] = *(const bf16x8*)(Lb + swz(r, kb)); }                            \
        _Pragma("unroll") for (int ni = 0; ni < 4; ++ni) {                           \
            int r = wn * 64 + ni * 16 + (lane & 15);                                 \
            bfr[ni] = *(const bf16x8*)(Lb + 16384 + swz(r, kb)); }                   \
        _Pragma("unroll") for (int mi = 0; mi < 4; ++mi)                             \
        _Pragma("unroll") for (int ni = 0; ni < 4; ++ni)                             \
            acc[mi][ni] = __builtin_amdgcn_mfma_f32_16x16x32_bf16(                   \
                af[mi], bfr[ni], acc[mi][ni], 0, 0, 0); } } while (0)

    LOAD_TILE(0);
    WRITE_TILE(0);
    __syncthreads();
    int cur = 0;
    for (int t = 0; t < NKT; ++t) {
        if (t + 1 < NKT) {
            LOAD_TILE(t + 1);            // issue-early: HBM latency hides under MFMA
            COMPUTE(cur);
            WRITE_TILE(cur ^ 1);         // write-late into the other buffer
        } else {
            COMPUTE(cur);
        }
        __syncthreads();                 // single barrier per K-tile
        cur ^= 1;
    }

    // epilogue: D frag col=lane&15 (n), row=(lane>>4)*4+q (m)  [m89-verified]
#pragma unroll
    for (int mi = 0; mi < 4; ++mi)
#pragma unroll
        for (int q = 0; q < 4; ++q) {
            int m = wm * 64 + mi * 16 + (lane >> 4) * 4 + q;
            int row = srow[m];
            if (row >= 0) {
#pragma unroll
                for (int ni = 0; ni < 4; ++ni)
                    out[(size_t)row * NF + nblk + wn * 64 + ni * 16 + (lane & 15)]
                        = acc[mi][ni][q];
            }
        }
}

extern "C" void kernel_launch(void* const* d_in, const int* in_sizes, int n_in,
                              void* d_out, int out_size, void* d_ws, size_t ws_size,
                              hipStream_t stream) {
    const float* inp    = (const float*)d_in[0];
    const int*   gate   = (const int*)d_in[1];
    const float* weight = (const float*)d_in[2];
    float*       out    = (float*)d_out;
    int*         ws     = (int*)d_ws;

    moe_prep<<<1, 1024, 0, stream>>>(gate, ws);
    moe_gemm<<<(NF / BN) * YT, 256, 0, stream>>>(inp, weight, ws, out);
}

// Round 4
// 30.932 us; speedup vs baseline: 1.8242x; 1.8242x over previous
//
#include <hip/hip_runtime.h>
#include <hip/hip_bf16.h>

// MoE: out[b] = inp[b] @ weight[gate[b]].T
// inp: [4096,512] f32, gate: [4096] int, weight: [32,512,512] f32, out: [4096,512] f32
// Round 4: 64x64x64 grouped bf16-MFMA GEMM. Shape 4096x512x512 only yields ~180
// blocks at 128^2 tiles (1 block/CU -> latency-bound, round-3 regression); 64^2
// gives ~550 blocks, 4-5 blocks/CU co-resident for wave-level overlap (m114).

#define NE     32
#define NBATCH 4096
#define KF     512
#define NF     512
#define BM     64            // token tile
#define BN     64            // out-feature tile
#define BK     64            // k tile
#define NKT    (KF / BK)     // 8
#define YT     96            // worst-case y tiles: 4096/64 + 31 = 95, pad 96

#define WS_COUNTS  0
#define WS_OFFSETS 32
#define WS_TABLE   64        // 96 entries
#define WS_TOKENS  256

typedef __attribute__((ext_vector_type(8))) short bf16x8;   // 8 bf16 = 4 VGPR
typedef __attribute__((ext_vector_type(4))) float f32x4;

__device__ __forceinline__ unsigned cvt2(float lo, float hi) {
    __hip_bfloat162 h = __float22bfloat162_rn(make_float2(lo, hi));
    return *reinterpret_cast<unsigned*>(&h);   // v_cvt_pk_bf16_f32
}

// XOR swizzle within [row][64 bf16] (128B row stride); same bijection write+read.
__device__ __forceinline__ int swz(int row, int col_b) {
    return (row * 128 + col_b) ^ ((row & 7) << 4);
}

// ---- fused prep: histogram + wave-scan + tile table + scatter, one block ----
__global__ __launch_bounds__(1024)
void moe_prep(const int* __restrict__ gate, int* __restrict__ ws) {
    __shared__ int cnt[NE], cur[NE];
    const int tid = threadIdx.x;
    if (tid < NE) cnt[tid] = 0;
    __syncthreads();
    int g[4];
#pragma unroll
    for (int i = 0; i < 4; ++i) {
        g[i] = gate[tid + i * 1024];
        atomicAdd(&cnt[g[i]], 1);
    }
    __syncthreads();
    if (tid < 64) {                       // wave 0 does both scans
        int c = (tid < NE) ? cnt[tid] : 0;
        int x = c;
#pragma unroll
        for (int d = 1; d < 32; d <<= 1) { int u = __shfl_up(x, d, 64); if (tid >= d) x += u; }
        int excl = x - c;                 // token offset
        if (tid < NE) {
            cur[tid] = excl;
            ws[WS_COUNTS + tid]  = c;
            ws[WS_OFFSETS + tid] = excl;
        }
        int nt = (c + BM - 1) / BM;       // tiles for this expert
        int t = nt;
#pragma unroll
        for (int d = 1; d < 32; d <<= 1) { int u = __shfl_up(t, d, 64); if (tid >= d) t += u; }
        int texcl = t - nt;
        int tot = __shfl(t, 31, 64);
        if (tid < NE)
            for (int k = 0; k < nt; ++k) ws[WS_TABLE + texcl + k] = (tid << 16) | k;
        for (int y = tid; y < YT; y += 64)
            if (y >= tot) ws[WS_TABLE + y] = -1;
    }
    __syncthreads();
#pragma unroll
    for (int i = 0; i < 4; ++i) {
        int pos = atomicAdd(&cur[g[i]], 1);
        ws[WS_TOKENS + pos] = tid + i * 1024;
    }
}

// ---- grouped MFMA GEMM: 64x64 tile, 4 waves, 32x32 per wave ----
__global__ __launch_bounds__(256)
void moe_gemm(const float* __restrict__ inp,
              const float* __restrict__ weight,
              const int* __restrict__ ws,
              float* __restrict__ out) {
    const int nb = blockIdx.x;            // n-tile (x fastest: same-y blocks adjacent)
    const int y  = blockIdx.y;

    const int entry = ws[WS_TABLE + y];
    if (entry < 0) return;
    const int e     = entry >> 16;
    const int local = entry & 0xffff;
    const int off   = ws[WS_OFFSETS + e];
    const int cnt   = ws[WS_COUNTS + e];
    const int* tokens = ws + WS_TOKENS;

    const int m0   = local * BM;
    const int mcnt = min(BM, cnt - m0);
    const int nblk = nb * BN;

    __shared__ __align__(16) unsigned char lds[2][(BM + BN) * BK * 2]; // 2 x 16KB
    __shared__ int srow[BM];

    const int tid  = threadIdx.x;
    const int lane = tid & 63;
    const int wid  = tid >> 6;
    const int wm   = wid & 1;             // m half (32 rows)
    const int wn   = wid >> 1;            // n half (32 cols)

    if (tid < BM) srow[tid] = (tid < mcnt) ? tokens[off + m0 + tid] : -1;
    __syncthreads();

    // rows this thread stages: slot s = tid + i*256 -> r = (tid>>4) + 16*i, i<4
    int arow[4];
#pragma unroll
    for (int i = 0; i < 4; ++i) arow[i] = srow[(tid >> 4) + 16 * i];

    const float* wbase = weight + (size_t)e * (NF * KF) + (size_t)nblk * KF;

    float4 ra[4], rw[4];

#define LOAD_TILE(T) do { const int k0 = (T) * BK; const int c4 = (tid & 15) * 4;    \
    _Pragma("unroll") for (int i = 0; i < 4; ++i) {                                  \
        ra[i] = (arow[i] >= 0)                                                       \
            ? *(const float4*)(inp + (size_t)arow[i] * KF + k0 + c4)                 \
            : make_float4(0.f, 0.f, 0.f, 0.f); }                                     \
    _Pragma("unroll") for (int i = 0; i < 4; ++i) {                                  \
        int r = (tid >> 4) + 16 * i;                                                 \
        rw[i] = *(const float4*)(wbase + (size_t)r * KF + k0 + c4); } } while (0)

#define WRITE_TILE(B) do { unsigned char* Lb = lds[B]; const int cb = (tid & 15) * 8;\
    _Pragma("unroll") for (int i = 0; i < 4; ++i) {                                  \
        int r = (tid >> 4) + 16 * i;                                                 \
        uint2 p = make_uint2(cvt2(ra[i].x, ra[i].y), cvt2(ra[i].z, ra[i].w));        \
        *(uint2*)(Lb + swz(r, cb)) = p; }                                            \
    _Pragma("unroll") for (int i = 0; i < 4; ++i) {                                  \
        int r = (tid >> 4) + 16 * i;                                                 \
        uint2 p = make_uint2(cvt2(rw[i].x, rw[i].y), cvt2(rw[i].z, rw[i].w));        \
        *(uint2*)(Lb + 8192 + swz(r, cb)) = p; } } while (0)

    f32x4 acc[2][2];
#pragma unroll
    for (int mi = 0; mi < 2; ++mi)
#pragma unroll
        for (int ni = 0; ni < 2; ++ni) acc[mi][ni] = (f32x4)(0.f);

#define COMPUTE(B) do { const unsigned char* Lb = lds[B];                            \
    _Pragma("unroll") for (int kk = 0; kk < 2; ++kk) {                               \
        const int kb = kk * 64 + 16 * (lane >> 4);                                   \
        bf16x8 af[2], bfr[2];                                                        \
        _Pragma("unroll") for (int mi = 0; mi < 2; ++mi) {                           \
            int r = wm * 32 + mi * 16 + (lane & 15);                                 \
            af[mi] = *(const bf16x8*)(Lb + swz(r, kb)); }                            \
        _Pragma("unroll") for (int ni = 0; ni < 2; ++ni) {                           \
            int r = wn * 32 + ni * 16 + (lane & 15);                                 \
            bfr[ni] = *(const bf16x8*)(Lb + 8192 + swz(r, kb)); }                    \
        _Pragma("unroll") for (int mi = 0; mi < 2; ++mi)                             \
        _Pragma("unroll") for (int ni = 0; ni < 2; ++ni)                             \
            acc[mi][ni] = __builtin_amdgcn_mfma_f32_16x16x32_bf16(                   \
                af[mi], bfr[ni], acc[mi][ni], 0, 0, 0); } } while (0)

    LOAD_TILE(0);
    WRITE_TILE(0);
    __syncthreads();
    int cur = 0;
    for (int t = 0; t < NKT; ++t) {
        if (t + 1 < NKT) {
            LOAD_TILE(t + 1);            // issue-early: latency hides under MFMA + other blocks
            COMPUTE(cur);
            WRITE_TILE(cur ^ 1);         // write-late into the other buffer
        } else {
            COMPUTE(cur);
        }
        __syncthreads();                 // single barrier per K-tile
        cur ^= 1;
    }

    // epilogue: D frag col=lane&15 (n), row=(lane>>4)*4+q (m)  [m89-verified]
#pragma unroll
    for (int mi = 0; mi < 2; ++mi)
#pragma unroll
        for (int q = 0; q < 4; ++q) {
            int m = wm * 32 + mi * 16 + (lane >> 4) * 4 + q;
            int row = srow[m];
            if (row >= 0) {
#pragma unroll
                for (int ni = 0; ni < 2; ++ni)
                    out[(size_t)row * NF + nblk + wn * 32 + ni * 16 + (lane & 15)]
                        = acc[mi][ni][q];
            }
        }
}

extern "C" void kernel_launch(void* const* d_in, const int* in_sizes, int n_in,
                              void* d_out, int out_size, void* d_ws, size_t ws_size,
                              hipStream_t stream) {
    const float* inp    = (const float*)d_in[0];
    const int*   gate   = (const int*)d_in[1];
    const float* weight = (const float*)d_in[2];
    float*       out    = (float*)d_out;
    int*         ws     = (int*)d_ws;

    moe_prep<<<1, 1024, 0, stream>>>(gate, ws);

    dim3 grid(NF / BN, YT);
    moe_gemm<<<grid, 256, 0, stream>>>(inp, weight, ws, out);
}